// Round 7
// baseline (529.499 us; speedup 1.0000x reference)
//
#include <hip/hip_runtime.h>
#include <math.h>

typedef __attribute__((ext_vector_type(8))) _Float16 half8;
typedef __attribute__((ext_vector_type(4))) float floatx4;

#define HMAP 160
#define WMAP 160
#define CIN 1024
#define NCOL 392
#define NCOLP 448
#define NPIX 25600
#define NROI 300
#define NALL 600

// output flat offsets (floats)
#define OUT_CLS      0
#define OUT_CLSRES   1200
#define OUT_CLSSCORE 1800
#define OUT_MASK     2400
#define OUT_ROISALL  237600
#define OUT_BBOX     240600
#define OUT_KEEP     243000

// ---------------------------------------------------------------------------
// async global->LDS, 16B per lane (fallback GEMM only)
// ---------------------------------------------------------------------------
typedef const __attribute__((address_space(1))) void gvoid_t;
typedef __attribute__((address_space(3))) void lvoid_t;
__device__ __forceinline__ void async16(const void* g, void* l) {
    __builtin_amdgcn_global_load_lds((gvoid_t*)g, (lvoid_t*)l, 16, 0, 0);
}

// ---------------------------------------------------------------------------
// Pre-convert W: Wt_hi/Wt_lo [448][1024] fp16 (transposed, zero-padded) +
// combined bias. lo scaled x4096 to stay fp16-normal.
// ---------------------------------------------------------------------------
__global__ __launch_bounds__(256) void convert_W(
    const float* __restrict__ Wps, const float* __restrict__ bps,
    const float* __restrict__ Wbb, const float* __restrict__ bbb,
    _Float16* __restrict__ Wth, _Float16* __restrict__ Wtl,
    float* __restrict__ bias_c)
{
    const int col = blockIdx.x;      // 0..447
    const int t = threadIdx.x;
    const bool isps = col < 196;
    const bool valid = col < NCOL;
    const float* W = isps ? Wps : Wbb;
    const int c = isps ? col : col - 196;
    const int k0 = t * 4;
#pragma unroll
    for (int j = 0; j < 4; j++) {
        int k = k0 + j;
        float v = valid ? W[k * 196 + c] : 0.f;
        _Float16 hi = (_Float16)v;
        _Float16 lo = (_Float16)((v - (float)hi) * 4096.f);
        Wth[(size_t)col * CIN + k] = hi;
        Wtl[(size_t)col * CIN + k] = lo;
    }
    if (t == 0)
        bias_c[col] = (col < 196) ? bps[col] : (valid ? bbb[col - 196] : 0.f);
}

// ---------------------------------------------------------------------------
// Pre-split A: feat fp32 [25600][1024] -> Ah, Al fp16 (lo x4096). Exactly the
// same numerics as the old in-loop split; removes cvt VALU from the K-loop and
// leaves A L3-resident for the GEMM.
// ---------------------------------------------------------------------------
__global__ __launch_bounds__(256) void convert_A(
    const float* __restrict__ A, _Float16* __restrict__ Ah,
    _Float16* __restrict__ Al)
{
    const size_t i = ((size_t)blockIdx.x * 256 + threadIdx.x) * 8;
    floatx4 x0 = *(const floatx4*)(A + i);
    floatx4 x1 = *(const floatx4*)(A + i + 4);
    half8 h, l;
#pragma unroll
    for (int e = 0; e < 8; e++) {
        float v = (e < 4) ? x0[e] : x1[e - 4];
        _Float16 hi = (_Float16)v;
        h[e] = hi;
        l[e] = (_Float16)((v - (float)hi) * 4096.f);
    }
    *(half8*)(Ah + i) = h;
    *(half8*)(Al + i) = l;
}

// ---------------------------------------------------------------------------
// PRIMARY GEMM: barrier-free register pipeline. Block 128x64, 4 waves of
// 32 rows x 64 cols. No LDS staging, no __syncthreads in K-loop -> no vmcnt
// drain convoys (round-6's 1350cyc/chunk wall). A prefetch depth 3 (L3
// ~450cyc), B depth 2 (L1-hot). All buffer indices compile-time (named
// structs, period-6 unrolled loop) — dynamic indexing caused round-2's VALU
// explosion. fp16 hi/lo 3-term MFMA (fp32-accurate).
// ---------------------------------------------------------------------------
struct ABuf { half8 ah[2], al[2]; };     // strips rows +0..15, +16..31
struct BBuf { half8 bh[4], bl[4]; };     // 4 col-tiles of 16

__device__ __forceinline__ void loadAr(ABuf& A, int k,
    const _Float16* __restrict__ pAh, const _Float16* __restrict__ pAl)
{
    A.ah[0] = *(const half8*)(pAh + k);
    A.ah[1] = *(const half8*)(pAh + 16 * CIN + k);
    A.al[0] = *(const half8*)(pAl + k);
    A.al[1] = *(const half8*)(pAl + 16 * CIN + k);
}

__device__ __forceinline__ void loadBr(BBuf& B, int k,
    const _Float16* __restrict__ pBh, const _Float16* __restrict__ pBl)
{
#pragma unroll
    for (int n = 0; n < 4; n++) {
        B.bh[n] = *(const half8*)(pBh + (size_t)n * 16 * CIN + k);
        B.bl[n] = *(const half8*)(pBl + (size_t)n * 16 * CIN + k);
    }
}

__device__ __forceinline__ void computer(const ABuf& A, const BBuf& B,
    floatx4 (&accM)[2][4], floatx4 (&accC)[2][4])
{
#pragma unroll
    for (int n = 0; n < 4; n++) {
#pragma unroll
        for (int s = 0; s < 2; s++) {
            accM[s][n] = __builtin_amdgcn_mfma_f32_16x16x32_f16(
                A.ah[s], B.bh[n], accM[s][n], 0, 0, 0);
            accC[s][n] = __builtin_amdgcn_mfma_f32_16x16x32_f16(
                A.al[s], B.bh[n], accC[s][n], 0, 0, 0);
            accC[s][n] = __builtin_amdgcn_mfma_f32_16x16x32_f16(
                A.ah[s], B.bl[n], accC[s][n], 0, 0, 0);
        }
    }
}

__global__ __launch_bounds__(256, 2) void gemm_reg(
    const _Float16* __restrict__ Ah, const _Float16* __restrict__ Al,
    const _Float16* __restrict__ Bh, const _Float16* __restrict__ Bl,
    const float* __restrict__ bias_c, float* __restrict__ Ct)
{
    __shared__ float tr[64 * 129];       // epilogue transpose only

    const int id = blockIdx.x;           // 0..1399
    const int xcd = id & 7, g = id >> 3; // XCD x owns bm [25x, 25x+25)
    const int lin = xcd * 175 + g;
    const int bm = lin / 7, bn = lin % 7;

    const int t = threadIdx.x;
    const int lane = t & 63, wave = t >> 6;
    const int l15 = lane & 15, lq = lane >> 4;

    const size_t arow = (size_t)(bm * 128 + wave * 32 + l15) * CIN + lq * 8;
    const _Float16* pAh = Ah + arow;
    const _Float16* pAl = Al + arow;
    const size_t cb = (size_t)(bn * 64 + l15) * CIN + lq * 8;
    const _Float16* pBh = Bh + cb;
    const _Float16* pBl = Bl + cb;

    floatx4 accM[2][4], accC[2][4];
#pragma unroll
    for (int s = 0; s < 2; s++)
#pragma unroll
        for (int n = 0; n < 4; n++) {
            accM[s][n] = (floatx4){0.f, 0.f, 0.f, 0.f};
            accC[s][n] = (floatx4){0.f, 0.f, 0.f, 0.f};
        }

    ABuf A0, A1, A2;
    BBuf B0, B1;
    loadAr(A0, 0, pAh, pAl);
    loadAr(A1, 32, pAh, pAl);
    loadAr(A2, 64, pAh, pAl);
    loadBr(B0, 0, pBh, pBl);
    loadBr(B1, 32, pBh, pBl);

    // chunk c (K=32) uses A[c%3], B[c%2]; A distance 3 chunks, B distance 2
#pragma unroll 1
    for (int it = 0; it < 5; ++it) {     // 6 chunks per iter, chunks 0..29
        const int kb = it * 192;
        computer(A0, B0, accM, accC);    // c = 6it
        loadAr(A0, kb + 96, pAh, pAl);  loadBr(B0, kb + 64, pBh, pBl);
        computer(A1, B1, accM, accC);    // c+1
        loadAr(A1, kb + 128, pAh, pAl); loadBr(B1, kb + 96, pBh, pBl);
        computer(A2, B0, accM, accC);    // c+2
        loadAr(A2, kb + 160, pAh, pAl); loadBr(B0, kb + 128, pBh, pBl);
        computer(A0, B1, accM, accC);    // c+3
        loadAr(A0, kb + 192, pAh, pAl); loadBr(B1, kb + 160, pBh, pBl);
        computer(A1, B0, accM, accC);    // c+4
        loadAr(A1, kb + 224, pAh, pAl); loadBr(B0, kb + 192, pBh, pBl);
        computer(A2, B1, accM, accC);    // c+5
        if (it < 4) loadAr(A2, kb + 256, pAh, pAl);
        loadBr(B1, kb + 224, pBh, pBl);
    }
    computer(A0, B0, accM, accC);        // chunk 30 (k=960)
    computer(A1, B1, accM, accC);        // chunk 31 (k=992)

    // epilogue: combine, transpose via LDS, store Ct[col][pix] coalesced
#pragma unroll
    for (int s = 0; s < 2; s++)
#pragma unroll
        for (int n = 0; n < 4; n++) {
            int colL = n * 16 + l15;
            int rowL = wave * 32 + s * 16 + lq * 4;
#pragma unroll
            for (int r = 0; r < 4; r++) {
                float v = accM[s][n][r] + accC[s][n][r] * (1.f / 4096.f);
                tr[colL * 129 + rowL + r] = v;
            }
        }
    __syncthreads();
    {
        const int colL = t >> 2, seg = t & 3;
        const int gcol = bn * 64 + colL;
        if (gcol < NCOL) {
            const float bias = bias_c[gcol];
            float* dst = Ct + (size_t)gcol * NPIX + bm * 128 + seg * 32;
            const float* src = &tr[colL * 129 + seg * 32];
#pragma unroll
            for (int i = 0; i < 8; i++) {
                floatx4 v = *(const floatx4*)(src + i * 4);
                v.x += bias; v.y += bias; v.z += bias; v.w += bias;
                *(floatx4*)(dst + i * 4) = v;
            }
        }
    }
}

// ---------------------------------------------------------------------------
// FALLBACK GEMM (round-6 LDS version) — used if ws_size can't hold Ah/Al.
// ---------------------------------------------------------------------------
__device__ __forceinline__ void stageA64(float* buf, const float* Abase,
                                         int k0, int t)
{
    const int lane = t & 63, w = t >> 6;
    const int r8 = lane & 7, quad = lane >> 3;
#pragma unroll
    for (int j = 0; j < 2; j++) {
        const float* gp = Abase + (size_t)(j * 32 + w * 8 + r8) * CIN
                          + k0 + quad * 4;
        float* lp = buf + (j * 4 + w) * 256;
        async16(gp, lp);
    }
}

__device__ __forceinline__ void stageB64(_Float16* buf,
                                         const _Float16* src, int t)
{
    const int lane = t & 63, w = t >> 6;
    const _Float16* gp = src + (size_t)(w * 16 + (lane & 15)) * CIN
                         + (lane >> 4) * 8;
    async16(gp, buf + w * 512);
}

__device__ __forceinline__ void mkfrag(const float* buf, int offA, int lq,
                                       half8& h, half8& l)
{
    floatx4 x0 = *(const floatx4*)(buf + offA + (2 * lq) * 32);
    floatx4 x1 = *(const floatx4*)(buf + offA + (2 * lq + 1) * 32);
#pragma unroll
    for (int e = 0; e < 8; e++) {
        float v = (e < 4) ? x0[e] : x1[e - 4];
        _Float16 hi = (_Float16)v;
        h[e] = hi;
        l[e] = (_Float16)((v - (float)hi) * 4096.f);
    }
}

__device__ __forceinline__ void mfma_chunk(
    const float* bufA, const _Float16* bufBh, const _Float16* bufBl,
    int offA, int lq, int boff, floatx4 (&accM)[4], floatx4 (&accC)[4])
{
    half8 ah, al;
    mkfrag(bufA, offA, lq, ah, al);
#pragma unroll
    for (int n = 0; n < 4; n++) {
        half8 bh = *(const half8*)(bufBh + n * 512 + boff);
        half8 bl = *(const half8*)(bufBl + n * 512 + boff);
        accM[n] = __builtin_amdgcn_mfma_f32_16x16x32_f16(ah, bh, accM[n], 0, 0, 0);
        accC[n] = __builtin_amdgcn_mfma_f32_16x16x32_f16(al, bh, accC[n], 0, 0, 0);
        accC[n] = __builtin_amdgcn_mfma_f32_16x16x32_f16(ah, bl, accC[n], 0, 0, 0);
    }
}

__global__ __launch_bounds__(256, 4) void gemm_lds(
    const float* __restrict__ A, const _Float16* __restrict__ Bh,
    const _Float16* __restrict__ Bl, const float* __restrict__ bias_c,
    float* __restrict__ Ct)
{
    __shared__ __align__(16) float smem[8192];
    float* bufA0 = smem;
    float* bufA1 = smem + 2048;
    _Float16* bufBh0 = (_Float16*)(smem + 4096);
    _Float16* bufBl0 = (_Float16*)(smem + 5120);
    _Float16* bufBh1 = (_Float16*)(smem + 6144);
    _Float16* bufBl1 = (_Float16*)(smem + 7168);

    const int id = blockIdx.x;
    const int xcd = id & 7, g = id >> 3;
    const int lin = xcd * 350 + g;
    const int bm = lin / 7, bn = lin % 7;

    const int t = threadIdx.x;
    const int lane = t & 63, wave = t >> 6;
    const int l15 = lane & 15, lq = lane >> 4;

    const float* Abase = A + (size_t)bm * 64 * CIN;
    const _Float16* Bhsrc = Bh + (size_t)bn * 64 * CIN;
    const _Float16* Blsrc = Bl + (size_t)bn * 64 * CIN;

    const int offA = (wave * 2 + (l15 >> 3)) * 256 + (l15 & 7) * 4;
    const int boff = lq * 128 + l15 * 8;

    floatx4 accM[4], accC[4];
#pragma unroll
    for (int n = 0; n < 4; n++) {
        accM[n] = (floatx4){0.f, 0.f, 0.f, 0.f};
        accC[n] = (floatx4){0.f, 0.f, 0.f, 0.f};
    }

    stageA64(bufA0, Abase, 0, t);
    stageB64(bufBh0, Bhsrc, t);
    stageB64(bufBl0, Blsrc, t);
    __syncthreads();

#pragma unroll 1
    for (int it = 0; it < 16; ++it) {
        const int k0 = it * 64;
        stageA64(bufA1, Abase, k0 + 32, t);
        stageB64(bufBh1, Bhsrc + k0 + 32, t);
        stageB64(bufBl1, Blsrc + k0 + 32, t);
        mfma_chunk(bufA0, bufBh0, bufBl0, offA, lq, boff, accM, accC);
        __syncthreads();
        if (it < 15) {
            stageA64(bufA0, Abase, k0 + 64, t);
            stageB64(bufBh0, Bhsrc + k0 + 64, t);
            stageB64(bufBl0, Blsrc + k0 + 64, t);
        }
        mfma_chunk(bufA1, bufBh1, bufBl1, offA, lq, boff, accM, accC);
        __syncthreads();
    }

    float* tr = smem;
#pragma unroll
    for (int n = 0; n < 4; n++) {
        int colL = n * 16 + l15;
        int rowL = wave * 16 + lq * 4;
#pragma unroll
        for (int r = 0; r < 4; r++) {
            float v = accM[n][r] + accC[n][r] * (1.f / 4096.f);
            tr[colL * 65 + rowL + r] = v;
        }
    }
    __syncthreads();
    {
        const int colL = t >> 2, seg = t & 3;
        const int gcol = bn * 64 + colL;
        if (gcol < NCOL) {
            const float bias = bias_c[gcol];
            float* dst = Ct + (size_t)gcol * NPIX + bm * 64 + seg * 16;
            const float* src = &tr[colL * 65 + seg * 16];
#pragma unroll
            for (int i = 0; i < 4; i++) {
                floatx4 v = *(const floatx4*)(src + i * 4);
                v.x += bias; v.y += bias; v.z += bias; v.w += bias;
                *(floatx4*)(dst + i * 4) = v;
            }
        }
    }
}

// ---------------------------------------------------------------------------
// bilinear setup for transposed maps [plane][160*160]
// ---------------------------------------------------------------------------
__device__ __forceinline__ void bil_setup2(
    float r1, float r2, float r3, float r4, int h, int w,
    int& o00, int& o01, int& o10, int& o11,
    float& w00, float& w01, float& w10, float& w11, int& ij)
{
    float x1 = r1 * 0.125f, y1 = r2 * 0.125f;
    float x2 = r3 * 0.125f, y2 = r4 * 0.125f;
    float bw = (x2 - x1) / 7.0f;
    float bh = (y2 - y1) / 7.0f;
    int i = h >> 1, sy = h & 1, j = w >> 1, sx = w & 1;
    float yy = y1 + ((float)i + ((float)sy + 0.5f) * 0.5f) * bh;
    float xx = x1 + ((float)j + ((float)sx + 0.5f) * 0.5f) * bw;
    float y0f = floorf(yy), x0f = floorf(xx);
    float wy = yy - y0f, wx = xx - x0f;
    int iy0 = min(max((int)y0f, 0), HMAP - 1);
    int iy1 = min(iy0 + 1, HMAP - 1);
    int ix0 = min(max((int)x0f, 0), WMAP - 1);
    int ix1 = min(ix0 + 1, WMAP - 1);
    o00 = iy0 * WMAP + ix0;
    o01 = iy0 * WMAP + ix1;
    o10 = iy1 * WMAP + ix0;
    o11 = iy1 * WMAP + ix1;
    w00 = (1.f - wy) * (1.f - wx);
    w01 = (1.f - wy) * wx;
    w10 = wy * (1.f - wx);
    w11 = wy * wx;
    ij = i * 7 + j;
}

__device__ __forceinline__ float samp(const float* __restrict__ p,
    int o00, int o01, int o10, int o11,
    float w00, float w01, float w10, float w11)
{
    return p[o00] * w00 + p[o01] * w01 + p[o10] * w10 + p[o11] * w11;
}

// ---------------------------------------------------------------------------
// part2_2 over original rois -> offsets -> proposals -> rois_all; bbox[0:300]
// ---------------------------------------------------------------------------
__global__ __launch_bounds__(256) void k_offsets_proposals(
    const float* __restrict__ maps, const float* __restrict__ rois,
    float* __restrict__ ws_roisall, float* __restrict__ out)
{
    const int r = blockIdx.x, t = threadIdx.x;
    __shared__ float4 red[256];
    const float* roi = rois + r * 5;
    const float r0 = roi[0], r1 = roi[1], r2 = roi[2], r3 = roi[3], r4 = roi[4];
    float4 v = make_float4(0.f, 0.f, 0.f, 0.f);
    if (t < 196) {
        int h = t / 14, w = t % 14;
        int o00, o01, o10, o11, ij;
        float w00, w01, w10, w11;
        bil_setup2(r1, r2, r3, r4, h, w, o00, o01, o10, o11, w00, w01, w10, w11, ij);
        float vals[4];
#pragma unroll
        for (int a = 0; a < 4; a++) {
            const float* p = maps + (size_t)(196 + a * 49 + ij) * NPIX;
            vals[a] = samp(p, o00, o01, o10, o11, w00, w01, w10, w11);
        }
        v = make_float4(vals[0], vals[1], vals[2], vals[3]);
    }
    red[t] = v;
    __syncthreads();
    for (int s = 128; s > 0; s >>= 1) {
        if (t < s) {
            red[t].x += red[t + s].x; red[t].y += red[t + s].y;
            red[t].z += red[t + s].z; red[t].w += red[t + s].w;
        }
        __syncthreads();
    }
    if (t == 0) {
        float dx = red[0].x / 196.f, dy = red[0].y / 196.f;
        float dw = red[0].z / 196.f, dh = red[0].w / 196.f;
        out[OUT_BBOX + r * 4 + 0] = dx;
        out[OUT_BBOX + r * 4 + 1] = dy;
        out[OUT_BBOX + r * 4 + 2] = dw;
        out[OUT_BBOX + r * 4 + 3] = dh;
        float w_ = r3 - r1 + 1.f, h_ = r4 - r2 + 1.f;
        float cx = r1 + 0.5f * w_, cy = r2 + 0.5f * h_;
        float pcx = dx * w_ + cx, pcy = dy * h_ + cy;
        float pw = expf(dw) * w_, ph = expf(dh) * h_;
        float px1 = fminf(fmaxf(pcx - 0.5f * pw, 0.f), 1279.f);
        float py1 = fminf(fmaxf(pcy - 0.5f * ph, 0.f), 1279.f);
        float px2 = fminf(fmaxf(pcx + 0.5f * pw, 0.f), 1279.f);
        float py2 = fminf(fmaxf(pcy + 0.5f * ph, 0.f), 1279.f);
        float rowA[5] = {r0, r1, r2, r3, r4};
        float rowB[5] = {0.f, px1, py1, px2, py2};
#pragma unroll
        for (int c = 0; c < 5; c++) {
            ws_roisall[r * 5 + c] = rowA[c];
            ws_roisall[(NROI + r) * 5 + c] = rowB[c];
            out[OUT_ROISALL + r * 5 + c] = rowA[c];
            out[OUT_ROISALL + (NROI + r) * 5 + c] = rowB[c];
        }
    }
}

// ---------------------------------------------------------------------------
// part2_1 over all 600 rois -> cls, cls_result, cls_score, mask_result
// PLUS (r >= 300) part2_2 bbox for proposal rois -> bbox[300:600]
// ---------------------------------------------------------------------------
__global__ __launch_bounds__(256) void k_cls_mask(
    const float* __restrict__ maps, const float* __restrict__ ws_roisall,
    float* __restrict__ scores_ws, float* __restrict__ out)
{
    const int r = blockIdx.x, t = threadIdx.x;
    __shared__ float4 vbuf[196];
    __shared__ float2 red[256];
    __shared__ float4 red4[256];
    __shared__ int s_cr;
    const float* roi = ws_roisall + r * 5;
    const float r1 = roi[1], r2 = roi[2], r3 = roi[3], r4 = roi[4];

    int o00 = 0, o01 = 0, o10 = 0, o11 = 0, ij = 0;
    float w00 = 0.f, w01 = 0.f, w10 = 0.f, w11 = 0.f;
    float2 cm = make_float2(0.f, 0.f);
    if (t < 196) {
        int h = t / 14, w = t % 14;
        bil_setup2(r1, r2, r3, r4, h, w, o00, o01, o10, o11, w00, w01, w10, w11, ij);
        float vals[4];
#pragma unroll
        for (int a = 0; a < 4; a++) {
            const float* p = maps + (size_t)(a * 49 + ij) * NPIX;
            vals[a] = samp(p, o00, o01, o10, o11, w00, w01, w10, w11);
        }
        vbuf[t] = make_float4(vals[0], vals[1], vals[2], vals[3]);
        cm.x = fmaxf(vals[0], vals[2]);
        cm.y = fmaxf(vals[1], vals[3]);
    }
    red[t] = cm;
    __syncthreads();
    for (int s = 128; s > 0; s >>= 1) {
        if (t < s) { red[t].x += red[t + s].x; red[t].y += red[t + s].y; }
        __syncthreads();
    }
    if (t == 0) {
        float a0 = red[0].x / 196.f, a1 = red[0].y / 196.f;
        float m = fmaxf(a0, a1);
        float e0 = expf(a0 - m), e1 = expf(a1 - m);
        float inv = 1.f / (e0 + e1);
        float c0 = e0 * inv, c1 = e1 * inv;
        int cr = (a1 > a0) ? 1 : 0;
        float cs = fmaxf(c0, c1);
        out[OUT_CLS + r * 2 + 0] = c0;
        out[OUT_CLS + r * 2 + 1] = c1;
        out[OUT_CLSRES + r] = (float)cr;
        out[OUT_CLSSCORE + r] = cs;
        scores_ws[r] = cs;
        s_cr = cr;
    }
    __syncthreads();
    if (t < 196) {
        int cr = s_cr;
        float4 vv = vbuf[t];
        float v0 = cr ? vv.y : vv.x;
        float v1 = cr ? vv.w : vv.z;
        float m = fmaxf(v0, v1);
        float e0 = expf(v0 - m), e1 = expf(v1 - m);
        float inv = 1.f / (e0 + e1);
        out[OUT_MASK + r * 392 + t * 2 + 0] = e0 * inv;
        out[OUT_MASK + r * 392 + t * 2 + 1] = e1 * inv;
    }

    if (r >= NROI) {
        float4 bv = make_float4(0.f, 0.f, 0.f, 0.f);
        if (t < 196) {
            float vals[4];
#pragma unroll
            for (int a = 0; a < 4; a++) {
                const float* p = maps + (size_t)(196 + a * 49 + ij) * NPIX;
                vals[a] = samp(p, o00, o01, o10, o11, w00, w01, w10, w11);
            }
            bv = make_float4(vals[0], vals[1], vals[2], vals[3]);
        }
        red4[t] = bv;
        __syncthreads();
        for (int s = 128; s > 0; s >>= 1) {
            if (t < s) {
                red4[t].x += red4[t + s].x; red4[t].y += red4[t + s].y;
                red4[t].z += red4[t + s].z; red4[t].w += red4[t + s].w;
            }
            __syncthreads();
        }
        if (t == 0) {
            out[OUT_BBOX + r * 4 + 0] = red4[0].x / 196.f;
            out[OUT_BBOX + r * 4 + 1] = red4[0].y / 196.f;
            out[OUT_BBOX + r * 4 + 2] = red4[0].z / 196.f;
            out[OUT_BBOX + r * 4 + 3] = red4[0].w / 196.f;
        }
    }
}

// ---------------------------------------------------------------------------
// NMS stage 1: stable descending rank-sort of scores; emit order + sorted boxes
// ---------------------------------------------------------------------------
__global__ __launch_bounds__(640) void k_sort(
    const float* __restrict__ scores_ws, const float* __restrict__ ws_roisall,
    int* __restrict__ order, float* __restrict__ sbox)
{
    __shared__ float ls[NALL];
    __shared__ float lb[NALL][4];
    const int t = threadIdx.x;
    if (t < NALL) {
        ls[t] = scores_ws[t];
        lb[t][0] = ws_roisall[t * 5 + 1];
        lb[t][1] = ws_roisall[t * 5 + 2];
        lb[t][2] = ws_roisall[t * 5 + 3];
        lb[t][3] = ws_roisall[t * 5 + 4];
    }
    __syncthreads();
    if (t < NALL) {
        float s = ls[t];
        int rank = 0;
        for (int j = 0; j < NALL; j++) {
            float sj = ls[j];
            rank += (sj > s) || (sj == s && j < t);
        }
        order[rank] = t;
        float x1 = lb[t][0], y1 = lb[t][1], x2 = lb[t][2], y2 = lb[t][3];
        sbox[rank]            = x1;
        sbox[NALL + rank]     = y1;
        sbox[2 * NALL + rank] = x2;
        sbox[3 * NALL + rank] = y2;
        sbox[4 * NALL + rank] = fmaxf(x2 - x1, 0.f) * fmaxf(y2 - y1, 0.f);
    }
}

// ---------------------------------------------------------------------------
// NMS stage 2: per sorted box i, 600-bit (iou>thr) mask as 10 uint64 words
// ---------------------------------------------------------------------------
__global__ __launch_bounds__(640) void k_iou_mask(
    const float* __restrict__ sbox, unsigned long long* __restrict__ mask)
{
    const int i = blockIdx.x, t = threadIdx.x;
    const float ix1 = sbox[i], iy1 = sbox[NALL + i];
    const float ix2 = sbox[2 * NALL + i], iy2 = sbox[3 * NALL + i];
    const float ia = sbox[4 * NALL + i];
    bool pred = false;
    if (t < NALL) {
        float jx1 = sbox[t], jy1 = sbox[NALL + t];
        float jx2 = sbox[2 * NALL + t], jy2 = sbox[3 * NALL + t];
        float ja = sbox[4 * NALL + t];
        float xx1 = fmaxf(ix1, jx1), yy1 = fmaxf(iy1, jy1);
        float xx2 = fminf(ix2, jx2), yy2 = fminf(iy2, jy2);
        float inter = fmaxf(xx2 - xx1, 0.f) * fmaxf(yy2 - yy1, 0.f);
        float iou = inter / (ia + ja - inter + 1e-8f);
        pred = iou > 0.3f;
    }
    unsigned long long b = __ballot(pred ? 1 : 0);
    if ((t & 63) == 0) mask[(size_t)i * 10 + (t >> 6)] = b;
}

// ---------------------------------------------------------------------------
// NMS stage 3: greedy suppression on LDS-staged masks + emit keep[300]
// ---------------------------------------------------------------------------
__global__ __launch_bounds__(256) void k_greedy(
    const unsigned long long* __restrict__ mask, const int* __restrict__ order,
    float* __restrict__ out)
{
    __shared__ unsigned long long lm[(NALL + 4) * 10];
    __shared__ unsigned long long kw[10];
    const int t = threadIdx.x;
    for (int i = t; i < NALL * 10; i += 256) lm[i] = mask[i];
    for (int i = NALL * 10 + t; i < (NALL + 4) * 10; i += 256) lm[i] = 0ull;
    __syncthreads();

    if (t < 64) {
        const int l = t;
        const bool act = l < 10;
        unsigned long long keepw = 0ull;
        unsigned long long c0 = act ? lm[0 * 10 + l] : 0ull;
        unsigned long long c1 = act ? lm[1 * 10 + l] : 0ull;
        unsigned long long c2 = act ? lm[2 * 10 + l] : 0ull;
        unsigned long long c3 = act ? lm[3 * 10 + l] : 0ull;
#pragma unroll 1
        for (int i = 0; i < NALL; i += 4) {
            bool s0 = __any((c0 & keepw) != 0ull);
            if (!s0 && l == (i >> 6)) keepw |= 1ull << (i & 63);
            c0 = act ? lm[(i + 4) * 10 + l] : 0ull;
            bool s1 = __any((c1 & keepw) != 0ull);
            if (!s1 && l == ((i + 1) >> 6)) keepw |= 1ull << ((i + 1) & 63);
            c1 = act ? lm[(i + 5) * 10 + l] : 0ull;
            bool s2 = __any((c2 & keepw) != 0ull);
            if (!s2 && l == ((i + 2) >> 6)) keepw |= 1ull << ((i + 2) & 63);
            c2 = act ? lm[(i + 6) * 10 + l] : 0ull;
            bool s3 = __any((c3 & keepw) != 0ull);
            if (!s3 && l == ((i + 3) >> 6)) keepw |= 1ull << ((i + 3) & 63);
            c3 = act ? lm[(i + 7) * 10 + l] : 0ull;
        }
        if (l < 10) kw[l] = keepw;
    }
    __syncthreads();
    if (t < 64) {
        int total = 0;
        for (int w = 0; w < 10; w++) total += __popcll(kw[w]);
        for (int tt = t; tt < 300; tt += 64) {
            float o = -1.f;
            if (tt < total) {
                int rem = tt, s = 0;
                for (int w = 0; w < 10; w++) {
                    int pc = __popcll(kw[w]);
                    if (rem >= pc) { rem -= pc; continue; }
                    unsigned long long word = kw[w];
                    while (rem--) word &= word - 1;
                    s = w * 64 + (__ffsll((long long)word) - 1);
                    break;
                }
                o = (float)order[s];
            }
            out[OUT_KEEP + tt] = o;
        }
    }
}

// ---------------------------------------------------------------------------
extern "C" void kernel_launch(void* const* d_in, const int* in_sizes, int n_in,
                              void* d_out, int out_size, void* d_ws, size_t ws_size,
                              hipStream_t stream)
{
    const float* feat = (const float*)d_in[0];
    const float* Wps  = (const float*)d_in[1];
    const float* bps  = (const float*)d_in[2];
    const float* Wbb  = (const float*)d_in[3];
    const float* bbb  = (const float*)d_in[4];
    const float* rois = (const float*)d_in[5];
    float* out = (float*)d_out;

    // workspace layout
    char* p = (char*)d_ws;
    float* maps_t = (float*)p;                      p += (size_t)NCOL * NPIX * 4;   // 40.14 MB
    _Float16* Wth = (_Float16*)p;                   p += (size_t)NCOLP * CIN * 2;
    _Float16* Wtl = (_Float16*)p;                   p += (size_t)NCOLP * CIN * 2;
    float* bias_c = (float*)p;                      p += NCOLP * 4;
    float* ws_roisall = (float*)p;                  p += NALL * 5 * 4;
    float* scores = (float*)p;                      p += NALL * 4;
    int* order = (int*)p;                           p += NALL * 4;
    float* sbox = (float*)p;                        p += NALL * 5 * 4;
    unsigned long long* mask = (unsigned long long*)p; p += NALL * 10 * 8;
    p = (char*)(((size_t)p + 255) & ~(size_t)255);
    _Float16* Ahs = (_Float16*)p;                   p += (size_t)NPIX * CIN * 2;    // 52.4 MB
    _Float16* Als = (_Float16*)p;                   p += (size_t)NPIX * CIN * 2;    // 52.4 MB
    const size_t need = (size_t)(p - (char*)d_ws);
    const bool big = ws_size >= need;

    hipLaunchKernelGGL(convert_W, dim3(NCOLP), dim3(256), 0, stream,
                       Wps, bps, Wbb, bbb, Wth, Wtl, bias_c);
    if (big) {
        hipLaunchKernelGGL(convert_A, dim3(12800), dim3(256), 0, stream,
                           feat, Ahs, Als);
        hipLaunchKernelGGL(gemm_reg, dim3(1400), dim3(256), 0, stream,
                           Ahs, Als, Wth, Wtl, bias_c, maps_t);
    } else {
        hipLaunchKernelGGL(gemm_lds, dim3(2800), dim3(256), 0, stream,
                           feat, Wth, Wtl, bias_c, maps_t);
    }
    hipLaunchKernelGGL(k_offsets_proposals, dim3(NROI), dim3(256), 0, stream,
                       maps_t, rois, ws_roisall, out);
    hipLaunchKernelGGL(k_cls_mask, dim3(NALL), dim3(256), 0, stream,
                       maps_t, ws_roisall, scores, out);
    hipLaunchKernelGGL(k_sort, dim3(1), dim3(640), 0, stream,
                       scores, ws_roisall, order, sbox);
    hipLaunchKernelGGL(k_iou_mask, dim3(NALL), dim3(640), 0, stream,
                       sbox, mask);
    hipLaunchKernelGGL(k_greedy, dim3(1), dim3(256), 0, stream,
                       mask, order, out);
}

// Round 8
// 366.793 us; speedup vs baseline: 1.4436x; 1.4436x over previous
//
#include <hip/hip_runtime.h>
#include <math.h>

typedef __attribute__((ext_vector_type(8))) _Float16 half8;
typedef __attribute__((ext_vector_type(4))) float floatx4;

#define HMAP 160
#define WMAP 160
#define CIN 1024
#define NCOL 392
#define NCOLP 512
#define NPIX 25600
#define NROI 300
#define NALL 600

// output flat offsets (floats)
#define OUT_CLS      0
#define OUT_CLSRES   1200
#define OUT_CLSSCORE 1800
#define OUT_MASK     2400
#define OUT_ROISALL  237600
#define OUT_BBOX     240600
#define OUT_KEEP     243000

// ---------------------------------------------------------------------------
// async global->LDS, 16B per lane. LDS dest = wave-uniform base + lane*16.
// ---------------------------------------------------------------------------
typedef const __attribute__((address_space(1))) void gvoid_t;
typedef __attribute__((address_space(3))) void lvoid_t;
__device__ __forceinline__ void async16(const void* g, void* l) {
    __builtin_amdgcn_global_load_lds((gvoid_t*)g, (lvoid_t*)l, 16, 0, 0);
}

// ---------------------------------------------------------------------------
// Pre-convert W: Wt_hi/Wt_lo [512][1024] fp16 (transposed, zero-padded) +
// combined bias. lo scaled x4096 to stay fp16-normal.
// ---------------------------------------------------------------------------
__global__ __launch_bounds__(256) void convert_W(
    const float* __restrict__ Wps, const float* __restrict__ bps,
    const float* __restrict__ Wbb, const float* __restrict__ bbb,
    _Float16* __restrict__ Wth, _Float16* __restrict__ Wtl,
    float* __restrict__ bias_c)
{
    const int col = blockIdx.x;      // 0..511
    const int t = threadIdx.x;
    const bool isps = col < 196;
    const bool valid = col < NCOL;
    const float* W = isps ? Wps : Wbb;
    const int c = isps ? col : col - 196;
    const int k0 = t * 4;
#pragma unroll
    for (int j = 0; j < 4; j++) {
        int k = k0 + j;
        float v = valid ? W[k * 196 + c] : 0.f;
        _Float16 hi = (_Float16)v;
        _Float16 lo = (_Float16)((v - (float)hi) * 4096.f);
        Wth[(size_t)col * CIN + k] = hi;
        Wtl[(size_t)col * CIN + k] = lo;
    }
    if (t == 0)
        bias_c[col] = (col < 196) ? bps[col] : (valid ? bbb[col - 196] : 0.f);
}

// ---------------------------------------------------------------------------
// GEMM: block 128x128, 4 waves in 2x2, each wave owns a 64x64 tile
// (4x4 of 16x16x32, acc 128 VGPR). This 4x's arithmetic intensity vs
// round-6: per block-chunk LDS = 32 KB staged + 64 KB frag reads = ~750 cyc
// vs MFMA 920 cyc/4 SIMDs — balanced (r6 was LDS-bound 3x: every wave
// re-read ALL of B). A staged fp32 (16 KB = same bytes as split fp16!),
// hi/lo split in-registers (VALU co-schedules with MFMA). async16 LDS
// layout == frag b128 layout: base + tile*1024 + lane*16, conflict-free.
// ---------------------------------------------------------------------------
__device__ __forceinline__ void stage_chunk(
    char* bufA, char* bufB,
    const float* __restrict__ Ablk, const _Float16* __restrict__ Bhblk,
    const _Float16* __restrict__ Blblk, int k0, int wave, int l15, int lq)
{
#pragma unroll
    for (int j = 0; j < 2; j++) {
        const int mt = wave * 2 + j;   // A row-tile and B col-tile this wave stages
#pragma unroll
        for (int h = 0; h < 2; h++) {
            const float* gp = Ablk + (size_t)(mt * 16 + l15) * CIN
                              + k0 + lq * 8 + h * 4;
            async16(gp, bufA + (mt * 2 + h) * 1024);
        }
        const _Float16* gph = Bhblk + (size_t)(mt * 16 + l15) * CIN + k0 + lq * 8;
        async16(gph, bufB + (mt * 2 + 0) * 1024);
        const _Float16* gpl = Blblk + (size_t)(mt * 16 + l15) * CIN + k0 + lq * 8;
        async16(gpl, bufB + (mt * 2 + 1) * 1024);
    }
}

__device__ __forceinline__ void compute_chunk(
    const char* bufA, const char* bufB, int wr, int wc, int lane,
    floatx4 (&accM)[4][4], floatx4 (&accC)[4][4])
{
    half8 ah[4], al[4];
#pragma unroll
    for (int i = 0; i < 4; i++) {
        const int mt = wr * 4 + i;
        floatx4 x0 = *(const floatx4*)(bufA + (mt * 2 + 0) * 1024 + lane * 16);
        floatx4 x1 = *(const floatx4*)(bufA + (mt * 2 + 1) * 1024 + lane * 16);
#pragma unroll
        for (int e = 0; e < 8; e++) {
            float v = (e < 4) ? x0[e] : x1[e - 4];
            _Float16 hi = (_Float16)v;
            ah[i][e] = hi;
            al[i][e] = (_Float16)((v - (float)hi) * 4096.f);
        }
    }
#pragma unroll
    for (int j = 0; j < 4; j++) {
        const int nt = wc * 4 + j;
        half8 bh = *(const half8*)(bufB + (nt * 2 + 0) * 1024 + lane * 16);
        half8 bl = *(const half8*)(bufB + (nt * 2 + 1) * 1024 + lane * 16);
#pragma unroll
        for (int i = 0; i < 4; i++)
            accM[i][j] = __builtin_amdgcn_mfma_f32_16x16x32_f16(
                ah[i], bh, accM[i][j], 0, 0, 0);
#pragma unroll
        for (int i = 0; i < 4; i++)
            accC[i][j] = __builtin_amdgcn_mfma_f32_16x16x32_f16(
                al[i], bh, accC[i][j], 0, 0, 0);
#pragma unroll
        for (int i = 0; i < 4; i++)
            accC[i][j] = __builtin_amdgcn_mfma_f32_16x16x32_f16(
                ah[i], bl, accC[i][j], 0, 0, 0);
    }
}

__global__ __launch_bounds__(256, 2) void gemm_mfma(
    const float* __restrict__ A, const _Float16* __restrict__ Bh,
    const _Float16* __restrict__ Bl, const float* __restrict__ bias_c,
    float* __restrict__ Ct)
{
    __shared__ __align__(16) char smem[65536];
    char* bufA0 = smem;            // 16 KB: A chunk fp32 (128 rows x 32 k)
    char* bufA1 = smem + 16384;
    char* bufB0 = smem + 32768;    // 16 KB: B chunk hi+lo (128 cols x 32 k)
    char* bufB1 = smem + 49152;

    const int id = blockIdx.x;            // 0..799
    const int xcd = id & 7, g = id >> 3;  // XCD x owns bm [25x, 25x+25)
    const int lin = xcd * 100 + g;
    const int bm = lin >> 2, bn = lin & 3;

    const int t = threadIdx.x;
    const int lane = t & 63, wave = t >> 6;
    const int wr = wave >> 1, wc = wave & 1;
    const int l15 = lane & 15, lq = lane >> 4;

    const float* Ablk = A + (size_t)bm * 128 * CIN;
    const _Float16* Bhblk = Bh + (size_t)bn * 128 * CIN;
    const _Float16* Blblk = Bl + (size_t)bn * 128 * CIN;

    floatx4 accM[4][4], accC[4][4];
#pragma unroll
    for (int i = 0; i < 4; i++)
#pragma unroll
        for (int j = 0; j < 4; j++) {
            accM[i][j] = (floatx4){0.f, 0.f, 0.f, 0.f};
            accC[i][j] = (floatx4){0.f, 0.f, 0.f, 0.f};
        }

    stage_chunk(bufA0, bufB0, Ablk, Bhblk, Blblk, 0, wave, l15, lq);
    __syncthreads();

#pragma unroll 1
    for (int it = 0; it < 16; ++it) {
        const int k0 = it * 64;
        stage_chunk(bufA1, bufB1, Ablk, Bhblk, Blblk, k0 + 32, wave, l15, lq);
        compute_chunk(bufA0, bufB0, wr, wc, lane, accM, accC);
        __syncthreads();
        if (it < 15)
            stage_chunk(bufA0, bufB0, Ablk, Bhblk, Blblk, k0 + 64, wave, l15, lq);
        compute_chunk(bufA1, bufB1, wr, wc, lane, accM, accC);
        __syncthreads();
    }

    // epilogue: combine + transpose via LDS in two 64-col passes, store
    // Ct[col][pix] coalesced
    float* tr = (float*)smem;    // 64 x 132 floats = 33 KB (aliases staging)
#pragma unroll 1
    for (int p = 0; p < 2; p++) {
        if (p) __syncthreads();
        if (wc == p) {
#pragma unroll
            for (int j = 0; j < 4; j++) {
                const int colL = j * 16 + l15;
                const int rowB = wr * 64 + lq * 4;
#pragma unroll
                for (int i = 0; i < 4; i++)
#pragma unroll
                    for (int r = 0; r < 4; r++)
                        tr[colL * 132 + rowB + i * 16 + r] =
                            accM[i][j][r] + accC[i][j][r] * (1.f / 4096.f);
            }
        }
        __syncthreads();
        {
            const int colL = t >> 2, seg = t & 3;
            const int gcol = bn * 128 + p * 64 + colL;
            if (gcol < NCOL) {
                const float bias = bias_c[gcol];
                float* dst = Ct + (size_t)gcol * NPIX + bm * 128 + seg * 32;
                const float* src = tr + colL * 132 + seg * 32;
#pragma unroll
                for (int i = 0; i < 8; i++) {
                    floatx4 v = *(const floatx4*)(src + i * 4);
                    v.x += bias; v.y += bias; v.z += bias; v.w += bias;
                    *(floatx4*)(dst + i * 4) = v;
                }
            }
        }
    }
}

// ---------------------------------------------------------------------------
// bilinear setup for transposed maps [plane][160*160]
// ---------------------------------------------------------------------------
__device__ __forceinline__ void bil_setup2(
    float r1, float r2, float r3, float r4, int h, int w,
    int& o00, int& o01, int& o10, int& o11,
    float& w00, float& w01, float& w10, float& w11, int& ij)
{
    float x1 = r1 * 0.125f, y1 = r2 * 0.125f;
    float x2 = r3 * 0.125f, y2 = r4 * 0.125f;
    float bw = (x2 - x1) / 7.0f;
    float bh = (y2 - y1) / 7.0f;
    int i = h >> 1, sy = h & 1, j = w >> 1, sx = w & 1;
    float yy = y1 + ((float)i + ((float)sy + 0.5f) * 0.5f) * bh;
    float xx = x1 + ((float)j + ((float)sx + 0.5f) * 0.5f) * bw;
    float y0f = floorf(yy), x0f = floorf(xx);
    float wy = yy - y0f, wx = xx - x0f;
    int iy0 = min(max((int)y0f, 0), HMAP - 1);
    int iy1 = min(iy0 + 1, HMAP - 1);
    int ix0 = min(max((int)x0f, 0), WMAP - 1);
    int ix1 = min(ix0 + 1, WMAP - 1);
    o00 = iy0 * WMAP + ix0;
    o01 = iy0 * WMAP + ix1;
    o10 = iy1 * WMAP + ix0;
    o11 = iy1 * WMAP + ix1;
    w00 = (1.f - wy) * (1.f - wx);
    w01 = (1.f - wy) * wx;
    w10 = wy * (1.f - wx);
    w11 = wy * wx;
    ij = i * 7 + j;
}

__device__ __forceinline__ float samp(const float* __restrict__ p,
    int o00, int o01, int o10, int o11,
    float w00, float w01, float w10, float w11)
{
    return p[o00] * w00 + p[o01] * w01 + p[o10] * w10 + p[o11] * w11;
}

// ---------------------------------------------------------------------------
// part2_2 over original rois -> offsets -> proposals -> rois_all; bbox[0:300]
// ---------------------------------------------------------------------------
__global__ __launch_bounds__(256) void k_offsets_proposals(
    const float* __restrict__ maps, const float* __restrict__ rois,
    float* __restrict__ ws_roisall, float* __restrict__ out)
{
    const int r = blockIdx.x, t = threadIdx.x;
    __shared__ float4 red[256];
    const float* roi = rois + r * 5;
    const float r0 = roi[0], r1 = roi[1], r2 = roi[2], r3 = roi[3], r4 = roi[4];
    float4 v = make_float4(0.f, 0.f, 0.f, 0.f);
    if (t < 196) {
        int h = t / 14, w = t % 14;
        int o00, o01, o10, o11, ij;
        float w00, w01, w10, w11;
        bil_setup2(r1, r2, r3, r4, h, w, o00, o01, o10, o11, w00, w01, w10, w11, ij);
        float vals[4];
#pragma unroll
        for (int a = 0; a < 4; a++) {
            const float* p = maps + (size_t)(196 + a * 49 + ij) * NPIX;
            vals[a] = samp(p, o00, o01, o10, o11, w00, w01, w10, w11);
        }
        v = make_float4(vals[0], vals[1], vals[2], vals[3]);
    }
    red[t] = v;
    __syncthreads();
    for (int s = 128; s > 0; s >>= 1) {
        if (t < s) {
            red[t].x += red[t + s].x; red[t].y += red[t + s].y;
            red[t].z += red[t + s].z; red[t].w += red[t + s].w;
        }
        __syncthreads();
    }
    if (t == 0) {
        float dx = red[0].x / 196.f, dy = red[0].y / 196.f;
        float dw = red[0].z / 196.f, dh = red[0].w / 196.f;
        out[OUT_BBOX + r * 4 + 0] = dx;
        out[OUT_BBOX + r * 4 + 1] = dy;
        out[OUT_BBOX + r * 4 + 2] = dw;
        out[OUT_BBOX + r * 4 + 3] = dh;
        float w_ = r3 - r1 + 1.f, h_ = r4 - r2 + 1.f;
        float cx = r1 + 0.5f * w_, cy = r2 + 0.5f * h_;
        float pcx = dx * w_ + cx, pcy = dy * h_ + cy;
        float pw = expf(dw) * w_, ph = expf(dh) * h_;
        float px1 = fminf(fmaxf(pcx - 0.5f * pw, 0.f), 1279.f);
        float py1 = fminf(fmaxf(pcy - 0.5f * ph, 0.f), 1279.f);
        float px2 = fminf(fmaxf(pcx + 0.5f * pw, 0.f), 1279.f);
        float py2 = fminf(fmaxf(pcy + 0.5f * ph, 0.f), 1279.f);
        float rowA[5] = {r0, r1, r2, r3, r4};
        float rowB[5] = {0.f, px1, py1, px2, py2};
#pragma unroll
        for (int c = 0; c < 5; c++) {
            ws_roisall[r * 5 + c] = rowA[c];
            ws_roisall[(NROI + r) * 5 + c] = rowB[c];
            out[OUT_ROISALL + r * 5 + c] = rowA[c];
            out[OUT_ROISALL + (NROI + r) * 5 + c] = rowB[c];
        }
    }
}

// ---------------------------------------------------------------------------
// part2_1 over all 600 rois -> cls, cls_result, cls_score, mask_result
// PLUS (r >= 300) part2_2 bbox for proposal rois -> bbox[300:600]
// ---------------------------------------------------------------------------
__global__ __launch_bounds__(256) void k_cls_mask(
    const float* __restrict__ maps, const float* __restrict__ ws_roisall,
    float* __restrict__ scores_ws, float* __restrict__ out)
{
    const int r = blockIdx.x, t = threadIdx.x;
    __shared__ float4 vbuf[196];
    __shared__ float2 red[256];
    __shared__ float4 red4[256];
    __shared__ int s_cr;
    const float* roi = ws_roisall + r * 5;
    const float r1 = roi[1], r2 = roi[2], r3 = roi[3], r4 = roi[4];

    int o00 = 0, o01 = 0, o10 = 0, o11 = 0, ij = 0;
    float w00 = 0.f, w01 = 0.f, w10 = 0.f, w11 = 0.f;
    float2 cm = make_float2(0.f, 0.f);
    if (t < 196) {
        int h = t / 14, w = t % 14;
        bil_setup2(r1, r2, r3, r4, h, w, o00, o01, o10, o11, w00, w01, w10, w11, ij);
        float vals[4];
#pragma unroll
        for (int a = 0; a < 4; a++) {
            const float* p = maps + (size_t)(a * 49 + ij) * NPIX;
            vals[a] = samp(p, o00, o01, o10, o11, w00, w01, w10, w11);
        }
        vbuf[t] = make_float4(vals[0], vals[1], vals[2], vals[3]);
        cm.x = fmaxf(vals[0], vals[2]);
        cm.y = fmaxf(vals[1], vals[3]);
    }
    red[t] = cm;
    __syncthreads();
    for (int s = 128; s > 0; s >>= 1) {
        if (t < s) { red[t].x += red[t + s].x; red[t].y += red[t + s].y; }
        __syncthreads();
    }
    if (t == 0) {
        float a0 = red[0].x / 196.f, a1 = red[0].y / 196.f;
        float m = fmaxf(a0, a1);
        float e0 = expf(a0 - m), e1 = expf(a1 - m);
        float inv = 1.f / (e0 + e1);
        float c0 = e0 * inv, c1 = e1 * inv;
        int cr = (a1 > a0) ? 1 : 0;
        float cs = fmaxf(c0, c1);
        out[OUT_CLS + r * 2 + 0] = c0;
        out[OUT_CLS + r * 2 + 1] = c1;
        out[OUT_CLSRES + r] = (float)cr;
        out[OUT_CLSSCORE + r] = cs;
        scores_ws[r] = cs;
        s_cr = cr;
    }
    __syncthreads();
    if (t < 196) {
        int cr = s_cr;
        float4 vv = vbuf[t];
        float v0 = cr ? vv.y : vv.x;
        float v1 = cr ? vv.w : vv.z;
        float m = fmaxf(v0, v1);
        float e0 = expf(v0 - m), e1 = expf(v1 - m);
        float inv = 1.f / (e0 + e1);
        out[OUT_MASK + r * 392 + t * 2 + 0] = e0 * inv;
        out[OUT_MASK + r * 392 + t * 2 + 1] = e1 * inv;
    }

    if (r >= NROI) {
        float4 bv = make_float4(0.f, 0.f, 0.f, 0.f);
        if (t < 196) {
            float vals[4];
#pragma unroll
            for (int a = 0; a < 4; a++) {
                const float* p = maps + (size_t)(196 + a * 49 + ij) * NPIX;
                vals[a] = samp(p, o00, o01, o10, o11, w00, w01, w10, w11);
            }
            bv = make_float4(vals[0], vals[1], vals[2], vals[3]);
        }
        red4[t] = bv;
        __syncthreads();
        for (int s = 128; s > 0; s >>= 1) {
            if (t < s) {
                red4[t].x += red4[t + s].x; red4[t].y += red4[t + s].y;
                red4[t].z += red4[t + s].z; red4[t].w += red4[t + s].w;
            }
            __syncthreads();
        }
        if (t == 0) {
            out[OUT_BBOX + r * 4 + 0] = red4[0].x / 196.f;
            out[OUT_BBOX + r * 4 + 1] = red4[0].y / 196.f;
            out[OUT_BBOX + r * 4 + 2] = red4[0].z / 196.f;
            out[OUT_BBOX + r * 4 + 3] = red4[0].w / 196.f;
        }
    }
}

// ---------------------------------------------------------------------------
// NMS stage 1: stable descending rank-sort of scores; emit order + sorted boxes
// ---------------------------------------------------------------------------
__global__ __launch_bounds__(640) void k_sort(
    const float* __restrict__ scores_ws, const float* __restrict__ ws_roisall,
    int* __restrict__ order, float* __restrict__ sbox)
{
    __shared__ float ls[NALL];
    __shared__ float lb[NALL][4];
    const int t = threadIdx.x;
    if (t < NALL) {
        ls[t] = scores_ws[t];
        lb[t][0] = ws_roisall[t * 5 + 1];
        lb[t][1] = ws_roisall[t * 5 + 2];
        lb[t][2] = ws_roisall[t * 5 + 3];
        lb[t][3] = ws_roisall[t * 5 + 4];
    }
    __syncthreads();
    if (t < NALL) {
        float s = ls[t];
        int rank = 0;
        for (int j = 0; j < NALL; j++) {
            float sj = ls[j];
            rank += (sj > s) || (sj == s && j < t);
        }
        order[rank] = t;
        float x1 = lb[t][0], y1 = lb[t][1], x2 = lb[t][2], y2 = lb[t][3];
        sbox[rank]            = x1;
        sbox[NALL + rank]     = y1;
        sbox[2 * NALL + rank] = x2;
        sbox[3 * NALL + rank] = y2;
        sbox[4 * NALL + rank] = fmaxf(x2 - x1, 0.f) * fmaxf(y2 - y1, 0.f);
    }
}

// ---------------------------------------------------------------------------
// NMS stage 2: per sorted box i, 600-bit (iou>thr) mask as 10 uint64 words
// ---------------------------------------------------------------------------
__global__ __launch_bounds__(640) void k_iou_mask(
    const float* __restrict__ sbox, unsigned long long* __restrict__ mask)
{
    const int i = blockIdx.x, t = threadIdx.x;
    const float ix1 = sbox[i], iy1 = sbox[NALL + i];
    const float ix2 = sbox[2 * NALL + i], iy2 = sbox[3 * NALL + i];
    const float ia = sbox[4 * NALL + i];
    bool pred = false;
    if (t < NALL) {
        float jx1 = sbox[t], jy1 = sbox[NALL + t];
        float jx2 = sbox[2 * NALL + t], jy2 = sbox[3 * NALL + t];
        float ja = sbox[4 * NALL + t];
        float xx1 = fmaxf(ix1, jx1), yy1 = fmaxf(iy1, jy1);
        float xx2 = fminf(ix2, jx2), yy2 = fminf(iy2, jy2);
        float inter = fmaxf(xx2 - xx1, 0.f) * fmaxf(yy2 - yy1, 0.f);
        float iou = inter / (ia + ja - inter + 1e-8f);
        pred = iou > 0.3f;
    }
    unsigned long long b = __ballot(pred ? 1 : 0);
    if ((t & 63) == 0) mask[(size_t)i * 10 + (t >> 6)] = b;
}

// ---------------------------------------------------------------------------
// NMS stage 3: greedy suppression on LDS-staged masks + emit keep[300]
// ---------------------------------------------------------------------------
__global__ __launch_bounds__(256) void k_greedy(
    const unsigned long long* __restrict__ mask, const int* __restrict__ order,
    float* __restrict__ out)
{
    __shared__ unsigned long long lm[(NALL + 4) * 10];
    __shared__ unsigned long long kw[10];
    const int t = threadIdx.x;
    for (int i = t; i < NALL * 10; i += 256) lm[i] = mask[i];
    for (int i = NALL * 10 + t; i < (NALL + 4) * 10; i += 256) lm[i] = 0ull;
    __syncthreads();

    if (t < 64) {
        const int l = t;
        const bool act = l < 10;
        unsigned long long keepw = 0ull;
        unsigned long long c0 = act ? lm[0 * 10 + l] : 0ull;
        unsigned long long c1 = act ? lm[1 * 10 + l] : 0ull;
        unsigned long long c2 = act ? lm[2 * 10 + l] : 0ull;
        unsigned long long c3 = act ? lm[3 * 10 + l] : 0ull;
#pragma unroll 1
        for (int i = 0; i < NALL; i += 4) {
            bool s0 = __any((c0 & keepw) != 0ull);
            if (!s0 && l == (i >> 6)) keepw |= 1ull << (i & 63);
            c0 = act ? lm[(i + 4) * 10 + l] : 0ull;
            bool s1 = __any((c1 & keepw) != 0ull);
            if (!s1 && l == ((i + 1) >> 6)) keepw |= 1ull << ((i + 1) & 63);
            c1 = act ? lm[(i + 5) * 10 + l] : 0ull;
            bool s2 = __any((c2 & keepw) != 0ull);
            if (!s2 && l == ((i + 2) >> 6)) keepw |= 1ull << ((i + 2) & 63);
            c2 = act ? lm[(i + 6) * 10 + l] : 0ull;
            bool s3 = __any((c3 & keepw) != 0ull);
            if (!s3 && l == ((i + 3) >> 6)) keepw |= 1ull << ((i + 3) & 63);
            c3 = act ? lm[(i + 7) * 10 + l] : 0ull;
        }
        if (l < 10) kw[l] = keepw;
    }
    __syncthreads();
    if (t < 64) {
        int total = 0;
        for (int w = 0; w < 10; w++) total += __popcll(kw[w]);
        for (int tt = t; tt < 300; tt += 64) {
            float o = -1.f;
            if (tt < total) {
                int rem = tt, s = 0;
                for (int w = 0; w < 10; w++) {
                    int pc = __popcll(kw[w]);
                    if (rem >= pc) { rem -= pc; continue; }
                    unsigned long long word = kw[w];
                    while (rem--) word &= word - 1;
                    s = w * 64 + (__ffsll((long long)word) - 1);
                    break;
                }
                o = (float)order[s];
            }
            out[OUT_KEEP + tt] = o;
        }
    }
}

// ---------------------------------------------------------------------------
extern "C" void kernel_launch(void* const* d_in, const int* in_sizes, int n_in,
                              void* d_out, int out_size, void* d_ws, size_t ws_size,
                              hipStream_t stream)
{
    const float* feat = (const float*)d_in[0];
    const float* Wps  = (const float*)d_in[1];
    const float* bps  = (const float*)d_in[2];
    const float* Wbb  = (const float*)d_in[3];
    const float* bbb  = (const float*)d_in[4];
    const float* rois = (const float*)d_in[5];
    float* out = (float*)d_out;

    // workspace layout
    char* p = (char*)d_ws;
    float* maps_t = (float*)p;                      p += (size_t)NCOL * NPIX * 4;   // 40.14 MB
    _Float16* Wth = (_Float16*)p;                   p += (size_t)NCOLP * CIN * 2;   // 1 MB
    _Float16* Wtl = (_Float16*)p;                   p += (size_t)NCOLP * CIN * 2;   // 1 MB
    float* bias_c = (float*)p;                      p += NCOLP * 4;
    float* ws_roisall = (float*)p;                  p += NALL * 5 * 4;
    float* scores = (float*)p;                      p += NALL * 4;
    int* order = (int*)p;                           p += NALL * 4;
    float* sbox = (float*)p;                        p += NALL * 5 * 4;
    unsigned long long* mask = (unsigned long long*)p;

    hipLaunchKernelGGL(convert_W, dim3(NCOLP), dim3(256), 0, stream,
                       Wps, bps, Wbb, bbb, Wth, Wtl, bias_c);
    hipLaunchKernelGGL(gemm_mfma, dim3(800), dim3(256), 0, stream,
                       feat, Wth, Wtl, bias_c, maps_t);
    hipLaunchKernelGGL(k_offsets_proposals, dim3(NROI), dim3(256), 0, stream,
                       maps_t, rois, ws_roisall, out);
    hipLaunchKernelGGL(k_cls_mask, dim3(NALL), dim3(256), 0, stream,
                       maps_t, ws_roisall, scores, out);
    hipLaunchKernelGGL(k_sort, dim3(1), dim3(640), 0, stream,
                       scores, ws_roisall, order, sbox);
    hipLaunchKernelGGL(k_iou_mask, dim3(NALL), dim3(640), 0, stream,
                       sbox, mask);
    hipLaunchKernelGGL(k_greedy, dim3(1), dim3(256), 0, stream,
                       mask, order, out);
}